// Round 10
// baseline (40.695 us; speedup 1.0000x reference)
//
#include <hip/hip_runtime.h>

// Ray-sphere intersection, split-K over spheres.
// x: (1, N, 7) f32 = [origin(3), t_ray(1), direction(3)]
// z: (1, 384) f32 = 64 spheres x [center(3), velocity(3)]
// out: mu (N) ++ sigma (N), f32
//
// Probe + potential win: every structural variant (R5-R9) pinned at ~34.5us
// with VALU pipe only ~58% busy and occupancy-insensitive -> hypothesis:
// slack scales with per-wave serial body length. Split spheres 2-way:
// 2x waves, each 2 rays x 32 spheres, combined via atomicMin on u32 bits.
//
// u32-min here is SAFE (unlike the banned R4/R7 in-loop bit tail): inputs are
// outputs of the PROVEN select tail -- strictly positive floats or BIG, never
// NaN/denormal-of-negative/+-0 -- where float order == unsigned order exactly.
// Min is commutative/idempotent -> replay-deterministic. Init kernel re-fills
// mu=BIG, sigma=0.002 every call (graph-captured, same stream, ordered).
//
// FROZEN ARITHMETIC (R3/R5/R8-proven, scalar form, elementwise identical):
//   oc = fmaf(v,t, c-o); b = fmaf(dx,ocx,fmaf(dy,ocy,dz*ocz));
//   csq = fmaf(ocx,ocx,fmaf(ocy,ocy,ocz*ocz)); disc = fmaf(b,b, 1.0f-csq);
//   sq = raw v_sqrt(disc) (disc<0 -> NaN -> compares false -> BIG);
//   r = t0>0 ? t0 : (t1>0 ? t1 : BIG).  Do not re-associate.

typedef unsigned int u32;

constexpr float BIGF = 1e10f;

__global__ __launch_bounds__(256) void init_kernel(float* __restrict__ out, int N)
{
    int i = blockIdx.x * 256 + threadIdx.x;   // N/4 threads
    float4* o = (float4*)out;
    int q = N / 4;
    if (i < q) {
        o[i]     = make_float4(BIGF, BIGF, BIGF, BIGF);        // mu slots
        o[q + i] = make_float4(0.002f, 0.002f, 0.002f, 0.002f); // sigma slots
    }
}

__global__ __launch_bounds__(256, 8) void ray_sphere_split(
    const float* __restrict__ x, const float* __restrict__ z,
    u32* __restrict__ outb, int N)
{
    int bid  = blockIdx.x;
    int half = bid >> 11;                      // 2048 blocks per sphere-half
    int tid  = (bid & 2047) * 256 + threadIdx.x;
    long n0  = (long)tid * 2;                  // 2 rays per thread

    // 14 floats, 8B-aligned -> 7x global_load_dwordx2 (mapping R8-proven)
    const float2* xr = (const float2*)(x + n0 * 7);
    float2 w0 = xr[0], w1 = xr[1], w2 = xr[2], w3 = xr[3],
           w4 = xr[4], w5 = xr[5], w6 = xr[6];

    float ox0 = w0.x, oy0 = w0.y, oz0 = w1.x, tr0 = w1.y,
          dx0 = w2.x, dy0 = w2.y, dz0 = w3.x;
    float ox1 = w3.y, oy1 = w4.x, oz1 = w4.y, tr1 = w5.x,
          dx1 = w5.y, dy1 = w6.x, dz1 = w6.y;

    // normalize d: d / (sqrt(|d|^2) + 1e-12)   (FROZEN)
    {
        float n2 = fmaf(dx0, dx0, fmaf(dy0, dy0, dz0 * dz0));
        float inv = __builtin_amdgcn_rcpf(__builtin_amdgcn_sqrtf(n2) + 1e-12f);
        dx0 *= inv; dy0 *= inv; dz0 *= inv;
    }
    {
        float n2 = fmaf(dx1, dx1, fmaf(dy1, dy1, dz1 * dz1));
        float inv = __builtin_amdgcn_rcpf(__builtin_amdgcn_sqrtf(n2) + 1e-12f);
        dx1 *= inv; dy1 *= inv; dz1 *= inv;
    }

    float clA = BIGF, clB = BIGF;

    const float* zh = z + half * 32 * 6;       // this half's 32 spheres

    #pragma unroll 16
    for (int s = 0; s < 32; ++s) {
        const float* zs = zh + s * 6;          // uniform -> s_load, SGPR
        float cx = zs[0], cy = zs[1], cz = zs[2];
        float vx = zs[3], vy = zs[4], vz = zs[5];

        // ---- ray A (FROZEN chain) ----
        {
            float ocx = fmaf(vx, tr0, cx - ox0);
            float ocy = fmaf(vy, tr0, cy - oy0);
            float ocz = fmaf(vz, tr0, cz - oz0);
            float b   = fmaf(dx0, ocx, fmaf(dy0, ocy, dz0 * ocz));
            float csq = fmaf(ocx, ocx, fmaf(ocy, ocy, ocz * ocz));
            float disc = fmaf(b, b, 1.0f - csq);
            float sq = __builtin_amdgcn_sqrtf(disc);
            float t0 = b - sq, t1 = b + sq;
            float r1 = (t1 > 0.0f) ? t1 : BIGF;
            float r  = (t0 > 0.0f) ? t0 : r1;
            clA = fminf(clA, r);
        }
        // ---- ray B (FROZEN chain) ----
        {
            float ocx = fmaf(vx, tr1, cx - ox1);
            float ocy = fmaf(vy, tr1, cy - oy1);
            float ocz = fmaf(vz, tr1, cz - oz1);
            float b   = fmaf(dx1, ocx, fmaf(dy1, ocy, dz1 * ocz));
            float csq = fmaf(ocx, ocx, fmaf(ocy, ocy, ocz * ocz));
            float disc = fmaf(b, b, 1.0f - csq);
            float sq = __builtin_amdgcn_sqrtf(disc);
            float t0 = b - sq, t1 = b + sq;
            float r1 = (t1 > 0.0f) ? t1 : BIGF;
            float r  = (t0 > 0.0f) ? t0 : r1;
            clB = fminf(clB, r);
        }
    }

    // clA/clB are strictly positive floats (or BIG): u32 order == float order.
    atomicMin(&outb[n0],     __float_as_uint(clA));
    atomicMin(&outb[n0 + 1], __float_as_uint(clB));
}

extern "C" void kernel_launch(void* const* d_in, const int* in_sizes, int n_in,
                              void* d_out, int out_size, void* d_ws, size_t ws_size,
                              hipStream_t stream) {
    const float* x = (const float*)d_in[0];
    const float* z = (const float*)d_in[1];
    float* out = (float*)d_out;
    int N = in_sizes[0] / 7;   // 1048576

    int initBlocks = (N / 4 + 255) / 256;   // 1024
    init_kernel<<<initBlocks, 256, 0, stream>>>(out, N);

    int blocks = 2 * ((N / 2 + 255) / 256); // 4096: 2048 per sphere-half
    ray_sphere_split<<<blocks, 256, 0, stream>>>(x, z, (u32*)out, N);
}